// Round 20
// baseline (262.790 us; speedup 1.0000x reference)
//
#include <hip/hip_runtime.h>
#include <hip/hip_bf16.h>
#include <math.h>

typedef __attribute__((ext_vector_type(8))) short short8;
typedef __attribute__((ext_vector_type(4))) float f32x4;
typedef __attribute__((ext_vector_type(4))) int int4v;

#define SCL 0.1803368801111204f   // 0.125 * log2(e): folds softmax scale + exp2 conversion

static __device__ __forceinline__ unsigned short f2bf(float f) {
  unsigned u = __float_as_uint(f);
  u = u + 0x7FFFu + ((u >> 16) & 1u);   // RNE
  return (unsigned short)(u >> 16);
}

// bare v_exp_f32 (D = 2^S0), bypasses any libm wrapper
static __device__ __forceinline__ float fexp2(float x) {
  float r;
  asm("v_exp_f32 %0, %1" : "=v"(r) : "v"(x));
  return r;
}

// monotonic float<->uint key (no NaNs in data)
static __device__ __forceinline__ unsigned keyof(float x) {
  unsigned u = __float_as_uint(x);
  return (u & 0x80000000u) ? ~u : (u | 0x80000000u);
}
static __device__ __forceinline__ float keyinv(unsigned k) {
  unsigned u = (k & 0x80000000u) ? (k & 0x7FFFFFFFu) : ~k;
  return __uint_as_float(u);
}

// DPP-based 64-lane reductions: offsets 1,2,4,8 on the VALU pipe, only 16/32 on DS.
#define DPP_RED_STEP(x, OP, CTRL) \
  x = OP(x, __int_as_float(__builtin_amdgcn_mov_dpp(__float_as_int(x), CTRL, 0xf, 0xf, true)))
static __device__ __forceinline__ void red_maxmin(float& mx, float& mn) {
  DPP_RED_STEP(mx, fmaxf, 0xB1); DPP_RED_STEP(mn, fminf, 0xB1);
  DPP_RED_STEP(mx, fmaxf, 0x4E); DPP_RED_STEP(mn, fminf, 0x4E);
  DPP_RED_STEP(mx, fmaxf, 0x141); DPP_RED_STEP(mn, fminf, 0x141);
  DPP_RED_STEP(mx, fmaxf, 0x140); DPP_RED_STEP(mn, fminf, 0x140);
  mx = fmaxf(mx, __shfl_xor(mx, 16)); mn = fminf(mn, __shfl_xor(mn, 16));
  mx = fmaxf(mx, __shfl_xor(mx, 32)); mn = fminf(mn, __shfl_xor(mn, 32));
}
#undef DPP_RED_STEP
static __device__ __forceinline__ float red_sum2(float s) {
#define DPP_ADD(x, CTRL) \
  x = x + __int_as_float(__builtin_amdgcn_mov_dpp(__float_as_int(x), CTRL, 0xf, 0xf, true))
  DPP_ADD(s, 0xB1); DPP_ADD(s, 0x4E); DPP_ADD(s, 0x141); DPP_ADD(s, 0x140);
#undef DPP_ADD
  s += __shfl_xor(s, 16);
  s += __shfl_xor(s, 32);
  return s;
}

// S: f32 [16][1024] XOR-swizzled (64KB). After wave w reads its row, the row's 4KB
// stripe is reused as that wave's LINEAR survivor list (packed u32: bf16(p)<<16 | col).
static __device__ __forceinline__ int saddr(int r, int c) {
  return ((r << 12) + (c << 2)) ^ ((r & 7) << 4);
}

// async global->LDS, 16B per lane (m97 pattern)
static __device__ __forceinline__ void gld_lds16(const unsigned short* g, unsigned short* l) {
  __builtin_amdgcn_global_load_lds(
      (const __attribute__((address_space(1))) void*)g,
      (__attribute__((address_space(3))) void*)l, 16, 0, 0);
}

// ---------------- f32 -> bf16, q/k/v fused (8/thread) ----------------
__global__ __launch_bounds__(256) void cvt3_k(const float* __restrict__ q,
                                              const float* __restrict__ k,
                                              const float* __restrict__ v,
                                              unsigned short* __restrict__ oq,
                                              unsigned short* __restrict__ ok,
                                              unsigned short* __restrict__ ov) {
  const int y = blockIdx.y;
  const float* in = (y == 0) ? q : (y == 1) ? k : v;
  unsigned short* out = (y == 0) ? oq : (y == 1) ? ok : ov;
  const int i = blockIdx.x * 256 + threadIdx.x;
  const f32x4* p = (const f32x4*)in + 2 * (size_t)i;
  f32x4 a = p[0], b = p[1];
  short8 r;
  r[0] = (short)f2bf(a[0]); r[1] = (short)f2bf(a[1]);
  r[2] = (short)f2bf(a[2]); r[3] = (short)f2bf(a[3]);
  r[4] = (short)f2bf(b[0]); r[5] = (short)f2bf(b[1]);
  r[6] = (short)f2bf(b[2]); r[7] = (short)f2bf(b[3]);
  ((short8*)out)[i] = r;
}

// ---------------- W [k][n] f32 -> Wt [n][k] bf16, 4 weights fused ----------------
__global__ __launch_bounds__(256) void wtrans4_k(const float* __restrict__ Wq,
                                                 const float* __restrict__ Wk,
                                                 const float* __restrict__ Wv,
                                                 const float* __restrict__ Wo,
                                                 unsigned short* __restrict__ Wqt,
                                                 unsigned short* __restrict__ Wkt,
                                                 unsigned short* __restrict__ Wvt,
                                                 unsigned short* __restrict__ Wot) {
  const int z = blockIdx.z;
  const float* W = (z == 0) ? Wq : (z == 1) ? Wk : (z == 2) ? Wv : Wo;
  unsigned short* Wt = (z == 0) ? Wqt : (z == 1) ? Wkt : (z == 2) ? Wvt : Wot;
  __shared__ float tile[32][33];
  const int tx = threadIdx.x, ty = threadIdx.y;
  const int x0 = blockIdx.x * 32, y0 = blockIdx.y * 32;
#pragma unroll
  for (int j = 0; j < 4; ++j)
    tile[ty + j * 8][tx] = W[(y0 + ty + j * 8) * 1024 + x0 + tx];
  __syncthreads();
#pragma unroll
  for (int j = 0; j < 4; ++j)
    Wt[(x0 + ty + j * 8) * 1024 + (y0 + tx)] = f2bf(tile[tx][ty + j * 8]);
}

// ---------------- 128x128 bf16 MFMA GEMM body, double-buffered LDS pipeline ----------------
// MODE 0: out bf16 [b][h][t][d]; MODE 1: out bf16 [b][h][d][t]; MODE 2: out f32 [m][n]
template <int MODE>
static __device__ __forceinline__ void gemm_body(unsigned short* As0, unsigned short* Bs0,
                                                 unsigned short* As1, unsigned short* Bs1,
                                                 const unsigned short* __restrict__ A,
                                                 const unsigned short* __restrict__ Bt,
                                                 const float* __restrict__ bias,
                                                 void* __restrict__ out,
                                                 const int m0, const int n0) {
  const int tid = threadIdx.x;
  const int lane = tid & 63, w = tid >> 6;
  const int wr = w >> 1, wc = w & 1;
  const int l15 = lane & 15, l4 = lane >> 4;
  f32x4 acc[4][4] = {};
  const int r0 = tid >> 2, s0 = (tid & 3) * 8;
  const int r1 = r0 + 64;
  const unsigned short* gA0 = A + (m0 + r0) * 1024 + s0;
  const unsigned short* gA1 = A + (m0 + r1) * 1024 + s0;
  const unsigned short* gB0 = Bt + (n0 + r0) * 1024 + s0;
  const unsigned short* gB1 = Bt + (n0 + r1) * 1024 + s0;
  const int oA0 = r0 * 32 + s0, oA1 = r1 * 32 + s0;

  gld_lds16(gA0, As0 + oA0);
  gld_lds16(gA1, As0 + oA1);
  gld_lds16(gB0, Bs0 + oA0);
  gld_lds16(gB1, Bs0 + oA1);
  __syncthreads();

  for (int kt = 0; kt < 32; ++kt) {
    if (kt < 31) {
      const int k0n = (kt + 1) * 32;
      unsigned short* Asn = (kt & 1) ? As0 : As1;
      unsigned short* Bsn = (kt & 1) ? Bs0 : Bs1;
      gld_lds16(gA0 + k0n, Asn + oA0);
      gld_lds16(gA1 + k0n, Asn + oA1);
      gld_lds16(gB0 + k0n, Bsn + oA0);
      gld_lds16(gB1 + k0n, Bsn + oA1);
    }
    const unsigned short* Asc = (kt & 1) ? As1 : As0;
    const unsigned short* Bsc = (kt & 1) ? Bs1 : Bs0;
    short8 af[4], bfr[4];
#pragma unroll
    for (int i = 0; i < 4; ++i) {
      af[i]  = *(const short8*)(Asc + (wr * 64 + i * 16 + l15) * 32 + l4 * 8);
      bfr[i] = *(const short8*)(Bsc + (wc * 64 + i * 16 + l15) * 32 + l4 * 8);
    }
#pragma unroll
    for (int i = 0; i < 4; ++i)
#pragma unroll
      for (int j = 0; j < 4; ++j)
        acc[i][j] = __builtin_amdgcn_mfma_f32_16x16x32_bf16(af[i], bfr[j], acc[i][j], 0, 0, 0);
    __syncthreads();   // drains prefetch vmcnt + protects buffer reuse
  }
#pragma unroll
  for (int i = 0; i < 4; ++i) {
#pragma unroll
    for (int j = 0; j < 4; ++j) {
      const int n = n0 + wc * 64 + j * 16 + l15;
      const float bv = bias[n];
#pragma unroll
      for (int r = 0; r < 4; ++r) {
        const int m = m0 + wr * 64 + i * 16 + l4 * 4 + r;
        const float v = acc[i][j][r] + bv;
        if (MODE == 2) {
          ((float*)out)[m * 1024 + n] = v;
        } else {
          const int bb = m >> 10, t = m & 1023, hh = n >> 6, dd = n & 63;
          const unsigned short bfv = f2bf(v);
          if (MODE == 0)
            ((unsigned short*)out)[(((bb << 4) + hh) * 1024 + t) * 64 + dd] = bfv;
          else
            ((unsigned short*)out)[(((bb << 4) + hh) * 64 + dd) * 1024 + t] = bfv;
        }
      }
    }
  }
}

// 768 blocks 1-D. XCD-chunked: xcd = bid&7 owns m-tiles [xcd*4, xcd*4+4) for all (z,n).
__global__ __launch_bounds__(256) void gemm_qkv_k(
    const unsigned short* qbf, const unsigned short* kbf, const unsigned short* vbf,
    const unsigned short* Wqt, const unsigned short* Wkt, const unsigned short* Wvt,
    const float* bq, const float* bk, const float* bv,
    unsigned short* Qh, unsigned short* Kh, unsigned short* Vtd) {
  __shared__ unsigned short As0[128 * 32], Bs0[128 * 32], As1[128 * 32], Bs1[128 * 32];
  const int bid = (int)blockIdx.x;
  const int xcd = bid & 7, idx = bid >> 3;      // idx in [0,96)
  const int z = idx >> 5;                       // 0..2
  const int rem = idx & 31;
  const int m0 = (xcd * 4 + (rem >> 3)) * 128;  // 4 m-tiles per XCD
  const int n0 = (rem & 7) * 128;               // n fastest
  const unsigned short* A  = (z == 0) ? qbf : ((z == 1) ? kbf : vbf);
  const unsigned short* Bt = (z == 0) ? Wqt : ((z == 1) ? Wkt : Wvt);
  const float* bias        = (z == 0) ? bq  : ((z == 1) ? bk  : bv);
  // V also in [b][h][t][d] layout now (sparse-gather PV reads V rows)
  if (z == 2) gemm_body<0>(As0, Bs0, As1, Bs1, A, Bt, bias, Vtd, m0, n0);
  else        gemm_body<0>(As0, Bs0, As1, Bs1, A, Bt, bias, z ? Kh : Qh, m0, n0);
}

// 256 blocks 1-D, same XCD chunking (4 m-tiles x 8 n-tiles per XCD).
__global__ __launch_bounds__(256) void gemm_out_k(const unsigned short* Y,
                                                  const unsigned short* Wot,
                                                  const float* bo, float* out) {
  __shared__ unsigned short As0[128 * 32], Bs0[128 * 32], As1[128 * 32], Bs1[128 * 32];
  const int bid = (int)blockIdx.x;
  const int xcd = bid & 7, idx = bid >> 3;      // idx in [0,32)
  const int m0 = (xcd * 4 + (idx >> 3)) * 128;
  const int n0 = (idx & 7) * 128;
  gemm_body<2>(As0, Bs0, As1, Bs1, Y, Wot, bo, out, m0, n0);
}

// ---------------- attention: 16 waves, one row/wave, ONE barrier, sparse-gather PV ----------------
// Grid: 4096 1-D blocks, XCD-chunked (T1). After the QK^T barrier each wave runs to
// completion independently: bisect -> compact survivors -> gather PV -> Y write.
// LDS: S f32[16][1024] (64KB); row stripes reused as per-wave survivor lists.
__global__ __launch_bounds__(1024, 8) void attn_k(const unsigned short* __restrict__ Q,
                                                  const unsigned short* __restrict__ K,
                                                  const unsigned short* __restrict__ Vt,
                                                  unsigned short* __restrict__ Y) {
  extern __shared__ __align__(16) char smem[];
  const int tid = threadIdx.x, lane = tid & 63, w = tid >> 6;
  const int bid = (int)blockIdx.x;
  const int wk = (bid & 7) * 512 + (bid >> 3);  // bijective: 4096 = 8 * 512
  const int hp = wk >> 6;                       // 0..63 = b*16 + h (head index)
  const int tc = wk & 63;
  const int t0 = 1008 - 16 * tc;                // heavy t-chunks first within each head
  const int b = hp >> 4, h = hp & 15;
  const unsigned short* Qp = Q + (((b * 16 + h) * 1024) + t0) * 64;
  const unsigned short* Kh = K + (b * 16 + h) * 65536;
  const unsigned short* Vh = Vt + (b * 16 + h) * 65536;   // [t][64] bf16
  const int L = t0 + 16;
  const int nCT = L >> 4;
  const bool full = (L > 512);                  // block-uniform
  const int l15 = lane & 15, l4 = lane >> 4;

  const short8 aq0 = *(const short8*)(Qp + l15 * 64 + l4 * 8);
  const short8 aq1 = *(const short8*)(Qp + l15 * 64 + 32 + l4 * 8);

  // ---- phase 1: QK^T, ONE pass over all column tiles ----
  for (int ct = w; ct < nCT; ct += 16) {
    const int c0 = ct * 16;
    const short8 kb0 = *(const short8*)(Kh + (c0 + l15) * 64 + l4 * 8);
    const short8 kb1 = *(const short8*)(Kh + (c0 + l15) * 64 + 32 + l4 * 8);
    f32x4 acc = {0.f, 0.f, 0.f, 0.f};
    __builtin_amdgcn_s_setprio(1);
    acc = __builtin_amdgcn_mfma_f32_16x16x32_bf16(aq0, kb0, acc, 0, 0, 0);
    acc = __builtin_amdgcn_mfma_f32_16x16x32_bf16(aq1, kb1, acc, 0, 0, 0);
    __builtin_amdgcn_s_setprio(0);
    const int c = c0 + l15;
    if (ct == nCT - 1) {                        // diagonal tile only (wave-uniform)
#pragma unroll
      for (int r = 0; r < 4; ++r) {
        const int row = l4 * 4 + r;
        *(float*)(smem + saddr(row, c)) = (c <= t0 + row) ? acc[r] * SCL : -INFINITY;
      }
    } else {
#pragma unroll
      for (int r = 0; r < 4; ++r)
        *(float*)(smem + saddr(l4 * 4 + r, c)) = acc[r] * SCL;
    }
  }
  __syncthreads();                              // the ONLY block-wide barrier

  // ---- phase 2a: wave w reads its row w (hoisted base + offset immediates) ----
  const int Lr = t0 + w + 1;
  const int sbase = (w << 12) | ((lane << 3) ^ ((w & 7) << 4));
  float v[16];
#pragma unroll
  for (int p = 0; p < 8; ++p) {
    const int c = (p << 7) + (lane << 1);
    const float2 t = *(const float2*)(smem + sbase + (p << 9));
    const bool vld = c < L;
    v[2 * p]     = vld ? t.x : -INFINITY;
    v[2 * p + 1] = vld ? t.y : -INFINITY;
  }

  // ---- phase 2b: max + min-of-lane-max (DPP tree) ----
  float lm = v[0];
#pragma unroll
  for (int i = 1; i < 16; ++i) lm = fmaxf(lm, v[i]);
  float mx = lm, mn = lm;
  red_maxmin(mx, mn);

  // ---- phase 2c: exact top-64 threshold (secant/midpoint bisection) ----
  auto countge = [&](float tm) {
    int cnt = 0;
#pragma unroll
    for (int i = 0; i < 8; ++i) cnt += (int)__popcll(__ballot(v[i] >= tm));
    if (full) {
#pragma unroll
      for (int i = 8; i < 16; ++i) cnt += (int)__popcll(__ballot(v[i] >= tm));
    }
    return cnt;
  };

  float thr = -INFINITY;
  if (Lr > 64) {                                // wave-uniform
    // proven bracket: min-of-lane-maxes has count >= 64; max+1 has count < 64
    unsigned lo = (unsigned)__builtin_amdgcn_readfirstlane((int)keyof(mn));
    unsigned hi = (unsigned)__builtin_amdgcn_readfirstlane((int)keyof(mx)) + 1u;
    int cl = Lr, ch = 0, alt = 0;
    for (int it = 0; it < 64 && (hi - lo) > 1u; ++it) {
      const unsigned span = hi - lo;
      unsigned off;
      if (alt) off = span >> 1;
      else {
        const float fr = (float)(cl - 64) / (float)(cl - ch);
        off = (unsigned)(fr * (float)span);
        if (off < 1u) off = 1u;
        if (off > span - 1u) off = span - 1u;
      }
      alt ^= 1;
      const unsigned mid = lo + off;
      const int cnt = countge(keyinv(mid));
      if (cnt >= 64) { lo = mid; cl = cnt; if (cnt == 64) hi = mid + 1u; }
      else { hi = mid; ch = cnt; }
    }
    thr = keyinv(lo);
  }

  // ---- phase 2d: compact survivors (bf16(exp)<<16 | col) into row-w stripe; sum ----
  // -inf entries excluded explicitly (handles thr = -inf for short rows).
  const int lbase = w << 12;                    // linear list; S row w fully consumed
  float s = 0.f;
  unsigned cnt = 0;
#pragma unroll
  for (int i = 0; i < 16; ++i) {
    const float p = fexp2(v[i] - mx);
    const bool pred = (v[i] >= thr) && (v[i] > -INFINITY);
    const unsigned long long mask = __ballot(pred);
    const unsigned pos = cnt + (unsigned)__popcll(mask & ((1ull << lane) - 1ull));
    if (pred) {
      const unsigned c = (unsigned)(((i >> 1) << 7) + (lane << 1) + (i & 1));
      *(unsigned*)(smem + lbase + (int)(pos << 2)) = ((unsigned)f2bf(p) << 16) | c;
      s += p;
    }
    cnt += (unsigned)__popcll(mask);
  }
  s = red_sum2(s);
  const float inv = 1.f / s;

  // ---- phase 3: sparse PV gather: y[t0+w][d=lane] = inv * sum_i p_i * V[t_i][lane] ----
  float acc = 0.f;
  const unsigned short* Vrow = Vh + lane;
  for (unsigned base = 0; base < cnt; base += 64) {
    unsigned vslot = 0u;
    if (base + (unsigned)lane < cnt)
      vslot = *(const unsigned*)(smem + lbase + (int)((base + lane) << 2));
    const unsigned m = (cnt - base < 64u) ? (cnt - base) : 64u;
#pragma unroll 4
    for (unsigned i = 0; i < m; ++i) {
      const unsigned u = (unsigned)__builtin_amdgcn_readlane((int)vslot, (int)i);
      const float p = __uint_as_float(u & 0xFFFF0000u);      // bf16<<16 == f32 bits
      const unsigned t = u & 1023u;
      const float vv = __uint_as_float(((unsigned)Vrow[t << 6]) << 16);
      acc = fmaf(p, vv, acc);
    }
  }
  Y[((b << 10) + t0 + w) * 1024 + (h << 6) + lane] = f2bf(acc * inv);
}

// ---------------- host ----------------
extern "C" void kernel_launch(void* const* d_in, const int* in_sizes, int n_in,
                              void* d_out, int out_size, void* d_ws, size_t ws_size,
                              hipStream_t stream) {
  const float* q  = (const float*)d_in[0];
  const float* k  = (const float*)d_in[1];
  const float* v  = (const float*)d_in[2];
  // d_in[3] = tgt_mask (causal tril) — computed analytically, not read
  const float* Wq = (const float*)d_in[4];
  const float* Wk = (const float*)d_in[5];
  const float* Wv = (const float*)d_in[6];
  const float* Wo = (const float*)d_in[7];
  const float* bq = (const float*)d_in[8];
  const float* bk = (const float*)d_in[9];
  const float* bv = (const float*)d_in[10];
  const float* bo = (const float*)d_in[11];

  char* ws = (char*)d_ws;
  const size_t MB = 1u << 20;
  unsigned short* qbf = (unsigned short*)(ws + 0 * MB);   // 8MB; reused as Y later
  unsigned short* kbf = (unsigned short*)(ws + 8 * MB);   // 8MB
  unsigned short* vbf = (unsigned short*)(ws + 16 * MB);  // 8MB
  unsigned short* Wqt = (unsigned short*)(ws + 24 * MB);  // 2MB
  unsigned short* Wkt = (unsigned short*)(ws + 26 * MB);  // 2MB
  unsigned short* Wvt = (unsigned short*)(ws + 28 * MB);  // 2MB
  unsigned short* Wot = (unsigned short*)(ws + 30 * MB);  // 2MB
  unsigned short* Qh  = (unsigned short*)(ws + 32 * MB);  // 8MB [b][h][t][d]
  unsigned short* Kh  = (unsigned short*)(ws + 40 * MB);  // 8MB [b][h][t][d]
  unsigned short* Vtd = (unsigned short*)(ws + 48 * MB);  // 8MB [b][h][t][d]
  unsigned short* Y   = qbf;  // alias: qbf is dead after gemm_qkv_k

  cvt3_k<<<dim3(2048, 3), 256, 0, stream>>>(q, k, v, qbf, kbf, vbf);
  wtrans4_k<<<dim3(32, 32, 4), dim3(32, 8), 0, stream>>>(Wq, Wk, Wv, Wo, Wqt, Wkt, Wvt, Wot);
  gemm_qkv_k<<<dim3(768), 256, 0, stream>>>(qbf, kbf, vbf, Wqt, Wkt, Wvt,
                                            bq, bk, bv, Qh, Kh, Vtd);
  attn_k<<<dim3(4096), 1024, 65536, stream>>>(Qh, Kh, Vtd, Y);
  gemm_out_k<<<dim3(256), 256, 0, stream>>>(Y, Wot, bo, (float*)d_out);
}

// Round 21
// 202.353 us; speedup vs baseline: 1.2987x; 1.2987x over previous
//
#include <hip/hip_runtime.h>
#include <hip/hip_bf16.h>
#include <math.h>

typedef __attribute__((ext_vector_type(8))) short short8;
typedef __attribute__((ext_vector_type(4))) float f32x4;
typedef __attribute__((ext_vector_type(4))) int int4v;

#define SCL 0.1803368801111204f   // 0.125 * log2(e): folds softmax scale + exp2 conversion

static __device__ __forceinline__ unsigned short f2bf(float f) {
  unsigned u = __float_as_uint(f);
  u = u + 0x7FFFu + ((u >> 16) & 1u);   // RNE
  return (unsigned short)(u >> 16);
}

// bare v_exp_f32 (D = 2^S0), bypasses any libm wrapper
static __device__ __forceinline__ float fexp2(float x) {
  float r;
  asm("v_exp_f32 %0, %1" : "=v"(r) : "v"(x));
  return r;
}

// monotonic float<->uint key (no NaNs in data)
static __device__ __forceinline__ unsigned keyof(float x) {
  unsigned u = __float_as_uint(x);
  return (u & 0x80000000u) ? ~u : (u | 0x80000000u);
}
static __device__ __forceinline__ float keyinv(unsigned k) {
  unsigned u = (k & 0x80000000u) ? (k & 0x7FFFFFFFu) : ~k;
  return __uint_as_float(u);
}

// DPP-based 64-lane reductions: offsets 1,2,4,8 on the VALU pipe, only 16/32 on DS.
#define DPP_RED_STEP(x, OP, CTRL) \
  x = OP(x, __int_as_float(__builtin_amdgcn_mov_dpp(__float_as_int(x), CTRL, 0xf, 0xf, true)))
static __device__ __forceinline__ void red_maxmin(float& mx, float& mn) {
  DPP_RED_STEP(mx, fmaxf, 0xB1); DPP_RED_STEP(mn, fminf, 0xB1);
  DPP_RED_STEP(mx, fmaxf, 0x4E); DPP_RED_STEP(mn, fminf, 0x4E);
  DPP_RED_STEP(mx, fmaxf, 0x141); DPP_RED_STEP(mn, fminf, 0x141);
  DPP_RED_STEP(mx, fmaxf, 0x140); DPP_RED_STEP(mn, fminf, 0x140);
  mx = fmaxf(mx, __shfl_xor(mx, 16)); mn = fminf(mn, __shfl_xor(mn, 16));
  mx = fmaxf(mx, __shfl_xor(mx, 32)); mn = fminf(mn, __shfl_xor(mn, 32));
}
#undef DPP_RED_STEP
static __device__ __forceinline__ float red_sum2(float s) {
#define DPP_ADD(x, CTRL) \
  x = x + __int_as_float(__builtin_amdgcn_mov_dpp(__float_as_int(x), CTRL, 0xf, 0xf, true))
  DPP_ADD(s, 0xB1); DPP_ADD(s, 0x4E); DPP_ADD(s, 0x141); DPP_ADD(s, 0x140);
#undef DPP_ADD
  s += __shfl_xor(s, 16);
  s += __shfl_xor(s, 32);
  return s;
}

// S: f32 [16][1024] XOR-swizzled (64KB). P: bf16 [16][1024] aliased into the LOW HALF of
// each S row's 4KB stripe. Row r of S and row r of P share the stripe -> per-row aliasing
// only. Swizzle decomposition (no carries cross the XOR field):
//   saddr(r, (p<<7)+(lane<<1)) = (r<<12) + (p<<9)  + ((lane<<3) ^ ((r&7)<<4))
//   paddr(r, (q<<7)+(lane<<1)) = (r<<12) + (q<<8)  + ((lane<<2) ^ ((r&7)<<4))
static __device__ __forceinline__ int saddr(int r, int c) {
  return ((r << 12) + (c << 2)) ^ ((r & 7) << 4);
}
static __device__ __forceinline__ int paddr(int r, int c) {
  return ((r << 12) + (c << 1)) ^ ((r & 7) << 4);
}

// async global->LDS, 16B per lane (m97 pattern)
static __device__ __forceinline__ void gld_lds16(const unsigned short* g, unsigned short* l) {
  __builtin_amdgcn_global_load_lds(
      (const __attribute__((address_space(1))) void*)g,
      (__attribute__((address_space(3))) void*)l, 16, 0, 0);
}

// ---------------- f32 -> bf16, q/k/v fused (8/thread) ----------------
__global__ __launch_bounds__(256) void cvt3_k(const float* __restrict__ q,
                                              const float* __restrict__ k,
                                              const float* __restrict__ v,
                                              unsigned short* __restrict__ oq,
                                              unsigned short* __restrict__ ok,
                                              unsigned short* __restrict__ ov) {
  const int y = blockIdx.y;
  const float* in = (y == 0) ? q : (y == 1) ? k : v;
  unsigned short* out = (y == 0) ? oq : (y == 1) ? ok : ov;
  const int i = blockIdx.x * 256 + threadIdx.x;
  const f32x4* p = (const f32x4*)in + 2 * (size_t)i;
  f32x4 a = p[0], b = p[1];
  short8 r;
  r[0] = (short)f2bf(a[0]); r[1] = (short)f2bf(a[1]);
  r[2] = (short)f2bf(a[2]); r[3] = (short)f2bf(a[3]);
  r[4] = (short)f2bf(b[0]); r[5] = (short)f2bf(b[1]);
  r[6] = (short)f2bf(b[2]); r[7] = (short)f2bf(b[3]);
  ((short8*)out)[i] = r;
}

// ---------------- W [k][n] f32 -> Wt [n][k] bf16, 4 weights fused ----------------
__global__ __launch_bounds__(256) void wtrans4_k(const float* __restrict__ Wq,
                                                 const float* __restrict__ Wk,
                                                 const float* __restrict__ Wv,
                                                 const float* __restrict__ Wo,
                                                 unsigned short* __restrict__ Wqt,
                                                 unsigned short* __restrict__ Wkt,
                                                 unsigned short* __restrict__ Wvt,
                                                 unsigned short* __restrict__ Wot) {
  const int z = blockIdx.z;
  const float* W = (z == 0) ? Wq : (z == 1) ? Wk : (z == 2) ? Wv : Wo;
  unsigned short* Wt = (z == 0) ? Wqt : (z == 1) ? Wkt : (z == 2) ? Wvt : Wot;
  __shared__ float tile[32][33];
  const int tx = threadIdx.x, ty = threadIdx.y;
  const int x0 = blockIdx.x * 32, y0 = blockIdx.y * 32;
#pragma unroll
  for (int j = 0; j < 4; ++j)
    tile[ty + j * 8][tx] = W[(y0 + ty + j * 8) * 1024 + x0 + tx];
  __syncthreads();
#pragma unroll
  for (int j = 0; j < 4; ++j)
    Wt[(x0 + ty + j * 8) * 1024 + (y0 + tx)] = f2bf(tile[tx][ty + j * 8]);
}

// ---------------- 128x128 bf16 MFMA GEMM body, double-buffered LDS pipeline ----------------
// MODE 0: out bf16 [b][h][t][d]; MODE 1: out bf16 [b][h][d][t]; MODE 2: out f32 [m][n]
template <int MODE>
static __device__ __forceinline__ void gemm_body(unsigned short* As0, unsigned short* Bs0,
                                                 unsigned short* As1, unsigned short* Bs1,
                                                 const unsigned short* __restrict__ A,
                                                 const unsigned short* __restrict__ Bt,
                                                 const float* __restrict__ bias,
                                                 void* __restrict__ out,
                                                 const int m0, const int n0) {
  const int tid = threadIdx.x;
  const int lane = tid & 63, w = tid >> 6;
  const int wr = w >> 1, wc = w & 1;
  const int l15 = lane & 15, l4 = lane >> 4;
  f32x4 acc[4][4] = {};
  const int r0 = tid >> 2, s0 = (tid & 3) * 8;
  const int r1 = r0 + 64;
  const unsigned short* gA0 = A + (m0 + r0) * 1024 + s0;
  const unsigned short* gA1 = A + (m0 + r1) * 1024 + s0;
  const unsigned short* gB0 = Bt + (n0 + r0) * 1024 + s0;
  const unsigned short* gB1 = Bt + (n0 + r1) * 1024 + s0;
  const int oA0 = r0 * 32 + s0, oA1 = r1 * 32 + s0;

  gld_lds16(gA0, As0 + oA0);
  gld_lds16(gA1, As0 + oA1);
  gld_lds16(gB0, Bs0 + oA0);
  gld_lds16(gB1, Bs0 + oA1);
  __syncthreads();

  for (int kt = 0; kt < 32; ++kt) {
    if (kt < 31) {
      const int k0n = (kt + 1) * 32;
      unsigned short* Asn = (kt & 1) ? As0 : As1;
      unsigned short* Bsn = (kt & 1) ? Bs0 : Bs1;
      gld_lds16(gA0 + k0n, Asn + oA0);
      gld_lds16(gA1 + k0n, Asn + oA1);
      gld_lds16(gB0 + k0n, Bsn + oA0);
      gld_lds16(gB1 + k0n, Bsn + oA1);
    }
    const unsigned short* Asc = (kt & 1) ? As1 : As0;
    const unsigned short* Bsc = (kt & 1) ? Bs1 : Bs0;
    short8 af[4], bfr[4];
#pragma unroll
    for (int i = 0; i < 4; ++i) {
      af[i]  = *(const short8*)(Asc + (wr * 64 + i * 16 + l15) * 32 + l4 * 8);
      bfr[i] = *(const short8*)(Bsc + (wc * 64 + i * 16 + l15) * 32 + l4 * 8);
    }
#pragma unroll
    for (int i = 0; i < 4; ++i)
#pragma unroll
      for (int j = 0; j < 4; ++j)
        acc[i][j] = __builtin_amdgcn_mfma_f32_16x16x32_bf16(af[i], bfr[j], acc[i][j], 0, 0, 0);
    __syncthreads();   // drains prefetch vmcnt + protects buffer reuse
  }
#pragma unroll
  for (int i = 0; i < 4; ++i) {
#pragma unroll
    for (int j = 0; j < 4; ++j) {
      const int n = n0 + wc * 64 + j * 16 + l15;
      const float bv = bias[n];
#pragma unroll
      for (int r = 0; r < 4; ++r) {
        const int m = m0 + wr * 64 + i * 16 + l4 * 4 + r;
        const float v = acc[i][j][r] + bv;
        if (MODE == 2) {
          ((float*)out)[m * 1024 + n] = v;
        } else {
          const int bb = m >> 10, t = m & 1023, hh = n >> 6, dd = n & 63;
          const unsigned short bfv = f2bf(v);
          if (MODE == 0)
            ((unsigned short*)out)[(((bb << 4) + hh) * 1024 + t) * 64 + dd] = bfv;
          else
            ((unsigned short*)out)[(((bb << 4) + hh) * 64 + dd) * 1024 + t] = bfv;
        }
      }
    }
  }
}

// 768 blocks 1-D. XCD-chunked: xcd = bid&7 owns m-tiles [xcd*4, xcd*4+4) for all (z,n).
__global__ __launch_bounds__(256) void gemm_qkv_k(
    const unsigned short* qbf, const unsigned short* kbf, const unsigned short* vbf,
    const unsigned short* Wqt, const unsigned short* Wkt, const unsigned short* Wvt,
    const float* bq, const float* bk, const float* bv,
    unsigned short* Qh, unsigned short* Kh, unsigned short* Vth) {
  __shared__ unsigned short As0[128 * 32], Bs0[128 * 32], As1[128 * 32], Bs1[128 * 32];
  const int bid = (int)blockIdx.x;
  const int xcd = bid & 7, idx = bid >> 3;      // idx in [0,96)
  const int z = idx >> 5;                       // 0..2
  const int rem = idx & 31;
  const int m0 = (xcd * 4 + (rem >> 3)) * 128;  // 4 m-tiles per XCD
  const int n0 = (rem & 7) * 128;               // n fastest
  const unsigned short* A  = (z == 0) ? qbf : ((z == 1) ? kbf : vbf);
  const unsigned short* Bt = (z == 0) ? Wqt : ((z == 1) ? Wkt : Wvt);
  const float* bias        = (z == 0) ? bq  : ((z == 1) ? bk  : bv);
  if (z == 2) gemm_body<1>(As0, Bs0, As1, Bs1, A, Bt, bias, Vth, m0, n0);
  else        gemm_body<0>(As0, Bs0, As1, Bs1, A, Bt, bias, z ? Kh : Qh, m0, n0);
}

// 256 blocks 1-D, same XCD chunking (4 m-tiles x 8 n-tiles per XCD).
__global__ __launch_bounds__(256) void gemm_out_k(const unsigned short* Y,
                                                  const unsigned short* Wot,
                                                  const float* bo, float* out) {
  __shared__ unsigned short As0[128 * 32], Bs0[128 * 32], As1[128 * 32], Bs1[128 * 32];
  const int bid = (int)blockIdx.x;
  const int xcd = bid & 7, idx = bid >> 3;      // idx in [0,32)
  const int m0 = (xcd * 4 + (idx >> 3)) * 128;
  const int n0 = (idx & 7) * 128;
  gemm_body<2>(As0, Bs0, As1, Bs1, Y, Wot, bo, out, m0, n0);
}

// ---------------- MERGED attention: 16 waves, one row/wave, single-pass f32 S ----------------
// Grid: 4096 1-D blocks. XCD-chunked swizzle (T1). Hoisted swizzle bases: per-lane LDS
// addressing in phases 2a/2d is base + compile-time offset (folds into ds offset imm).
// LDS: S f32[16][1024] (64KB, aliased per-row by P bf16) + RED3 [3][16][68] + RED2 [16]
__global__ __launch_bounds__(1024, 8) void attn_k(const unsigned short* __restrict__ Q,
                                                  const unsigned short* __restrict__ K,
                                                  const unsigned short* __restrict__ Vt,
                                                  unsigned short* __restrict__ Y) {
  extern __shared__ __align__(16) char smem[];
  const int tid = threadIdx.x, lane = tid & 63, w = tid >> 6;
  const int bid = (int)blockIdx.x;
  const int wk = (bid & 7) * 512 + (bid >> 3);  // bijective: 4096 = 8 * 512
  const int hp = wk >> 6;                       // 0..63 = b*16 + h (head index)
  const int tc = wk & 63;
  const int t0 = 1008 - 16 * tc;                // heavy t-chunks first within each head
  const int b = hp >> 4, h = hp & 15;
  const unsigned short* Qp = Q + (((b * 16 + h) * 1024) + t0) * 64;
  const unsigned short* Kh = K + (b * 16 + h) * 65536;
  const unsigned short* Vh = Vt + (b * 16 + h) * 65536;
  const int L = t0 + 16;
  const int Lpad = (L + 31) & ~31;
  const int nCT = L >> 4;
  const bool full = (L > 512);                  // block-uniform
  const int l15 = lane & 15, l4 = lane >> 4;
  float* RED3 = (float*)(smem + 65536);         // [3][16][68] f32
  float* RED2 = (float*)(smem + 65536 + 13056); // [16] f32

  const short8 aq0 = *(const short8*)(Qp + l15 * 64 + l4 * 8);
  const short8 aq1 = *(const short8*)(Qp + l15 * 64 + 32 + l4 * 8);

  // ---- phase 1: QK^T, ONE pass over all column tiles ----
  for (int ct = w; ct < nCT; ct += 16) {
    const int c0 = ct * 16;
    const short8 kb0 = *(const short8*)(Kh + (c0 + l15) * 64 + l4 * 8);
    const short8 kb1 = *(const short8*)(Kh + (c0 + l15) * 64 + 32 + l4 * 8);
    f32x4 acc = {0.f, 0.f, 0.f, 0.f};
    __builtin_amdgcn_s_setprio(1);
    acc = __builtin_amdgcn_mfma_f32_16x16x32_bf16(aq0, kb0, acc, 0, 0, 0);
    acc = __builtin_amdgcn_mfma_f32_16x16x32_bf16(aq1, kb1, acc, 0, 0, 0);
    __builtin_amdgcn_s_setprio(0);
    const int c = c0 + l15;
    if (ct == nCT - 1) {                        // diagonal tile only (wave-uniform)
#pragma unroll
      for (int r = 0; r < 4; ++r) {
        const int row = l4 * 4 + r;
        *(float*)(smem + saddr(row, c)) = (c <= t0 + row) ? acc[r] * SCL : -INFINITY;
      }
    } else {
#pragma unroll
      for (int r = 0; r < 4; ++r)
        *(float*)(smem + saddr(l4 * 4 + r, c)) = acc[r] * SCL;
    }
  }
  __syncthreads();                              // (1) S complete

  // ---- phase 2a: wave w reads its row w (hoisted base + offset immediates) ----
  const int Lr = t0 + w + 1;
  const int sbase = (w << 12) | ((lane << 3) ^ ((w & 7) << 4));
  float v[16];
#pragma unroll
  for (int p = 0; p < 8; ++p) {
    const int c = (p << 7) + (lane << 1);
    const float2 t = *(const float2*)(smem + sbase + (p << 9));
    const bool vld = c < L;
    v[2 * p]     = vld ? t.x : -INFINITY;
    v[2 * p + 1] = vld ? t.y : -INFINITY;
  }

  // ---- phase 2b: max + min-of-lane-max (DPP tree) ----
  float lm = v[0];
#pragma unroll
  for (int i = 1; i < 16; ++i) lm = fmaxf(lm, v[i]);
  float mx = lm, mn = lm;
  red_maxmin(mx, mn);

  // ---- phase 2c: exact top-64 threshold (secant/midpoint bisection) ----
  auto countge = [&](float tm) {
    int cnt = 0;
#pragma unroll
    for (int i = 0; i < 8; ++i) cnt += (int)__popcll(__ballot(v[i] >= tm));
    if (full) {
#pragma unroll
      for (int i = 8; i < 16; ++i) cnt += (int)__popcll(__ballot(v[i] >= tm));
    }
    return cnt;
  };

  float thr = -INFINITY;
  if (Lr > 64) {                                // wave-uniform
    // proven bracket: min-of-lane-maxes has count >= 64; max+1 has count < 64
    unsigned lo = (unsigned)__builtin_amdgcn_readfirstlane((int)keyof(mn));
    unsigned hi = (unsigned)__builtin_amdgcn_readfirstlane((int)keyof(mx)) + 1u;
    int cl = Lr, ch = 0, alt = 0;
    for (int it = 0; it < 64 && (hi - lo) > 1u; ++it) {
      const unsigned span = hi - lo;
      unsigned off;
      if (alt) off = span >> 1;
      else {
        const float fr = (float)(cl - 64) / (float)(cl - ch);
        off = (unsigned)(fr * (float)span);
        if (off < 1u) off = 1u;
        if (off > span - 1u) off = span - 1u;
      }
      alt ^= 1;
      const unsigned mid = lo + off;
      const int cnt = countge(keyinv(mid));
      if (cnt >= 64) { lo = mid; cl = cnt; if (cnt == 64) hi = mid + 1u; }
      else { hi = mid; ch = cnt; }
    }
    thr = keyinv(lo);
  }

  // ---- phase 2d: unnormalized exp (bare v_exp_f32) -> packed bf16 -> P row w ----
  const int pbase = (w << 12) | ((lane << 2) ^ ((w & 7) << 4));
  float s = 0.f;
  unsigned pk[8];
#pragma unroll
  for (int p = 0; p < 4; ++p) {
    const float p0 = (v[2 * p]     >= thr) ? fexp2(v[2 * p]     - mx) : 0.f;
    const float p1 = (v[2 * p + 1] >= thr) ? fexp2(v[2 * p + 1] - mx) : 0.f;
    s += p0 + p1;
    pk[p] = (unsigned)f2bf(p0) | ((unsigned)f2bf(p1) << 16);
  }
  if (full) {
#pragma unroll
    for (int p = 4; p < 8; ++p) {
      const float p0 = (v[2 * p]     >= thr) ? fexp2(v[2 * p]     - mx) : 0.f;
      const float p1 = (v[2 * p + 1] >= thr) ? fexp2(v[2 * p + 1] - mx) : 0.f;
      s += p0 + p1;
      pk[p] = (unsigned)f2bf(p0) | ((unsigned)f2bf(p1) << 16);
    }
  }
#pragma unroll
  for (int p = 0; p < 4; ++p) {
    const int c = (p << 7) + (lane << 1);
    if (c < Lpad) *(unsigned*)(smem + pbase + (p << 8)) = pk[p];
  }
  if (full) {
#pragma unroll
    for (int p = 4; p < 8; ++p) {
      const int c = ((p & 3) << 7) + (lane << 1) + 512;
      if (c < Lpad) *(unsigned*)(smem + pbase + ((p & 3) << 8) + 1024) = pk[p];
    }
  }
  s = red_sum2(s);
  if (lane == 0) RED2[w] = 1.f / s;
  __syncthreads();                              // (2) all P rows + RED2 visible

  // ---- phase 3: y = P @ V, 4-way K-split over 16 waves + LDS reduction ----
  const int nST = Lpad >> 5;
  const int qd = (nST + 3) >> 2;
  const int kseg = w >> 2;
  const int d0 = (w & 3) * 16;
  int klo = kseg * qd, khi = klo + qd;
  if (klo > nST) klo = nST;
  if (khi > nST) khi = nST;
  f32x4 acc = {0.f, 0.f, 0.f, 0.f};
  for (int st = klo; st < khi; ++st) {
    const int sb = st * 32 + l4 * 8;
    const short8 paf = *(const short8*)(smem + paddr(l15, sb));
    const short8 vb = *(const short8*)(Vh + (d0 + l15) * 1024 + sb);
    __builtin_amdgcn_s_setprio(1);
    acc = __builtin_amdgcn_mfma_f32_16x16x32_bf16(paf, vb, acc, 0, 0, 0);
    __builtin_amdgcn_s_setprio(0);
  }
  if (kseg > 0) {
#pragma unroll
    for (int r = 0; r < 4; ++r)
      RED3[((kseg - 1) * 16 + l4 * 4 + r) * 68 + d0 + l15] = acc[r];
  }
  __syncthreads();                              // (3) partials visible
  if (kseg == 0) {
    const int d = (h << 6) + d0 + l15;
#pragma unroll
    for (int r = 0; r < 4; ++r) {
      const int row = l4 * 4 + r;
      const int col = d0 + l15;
      float sv = acc[r] + RED3[row * 68 + col] + RED3[(16 + row) * 68 + col] +
                 RED3[(32 + row) * 68 + col];
      Y[((b << 10) + t0 + row) * 1024 + d] = f2bf(sv * RED2[row]);
    }
  }
}

// ---------------- host ----------------
extern "C" void kernel_launch(void* const* d_in, const int* in_sizes, int n_in,
                              void* d_out, int out_size, void* d_ws, size_t ws_size,
                              hipStream_t stream) {
  const float* q  = (const float*)d_in[0];
  const float* k  = (const float*)d_in[1];
  const float* v  = (const float*)d_in[2];
  // d_in[3] = tgt_mask (causal tril) — computed analytically, not read
  const float* Wq = (const float*)d_in[4];
  const float* Wk = (const float*)d_in[5];
  const float* Wv = (const float*)d_in[6];
  const float* Wo = (const float*)d_in[7];
  const float* bq = (const float*)d_in[8];
  const float* bk = (const float*)d_in[9];
  const float* bv = (const float*)d_in[10];
  const float* bo = (const float*)d_in[11];

  char* ws = (char*)d_ws;
  const size_t MB = 1u << 20;
  unsigned short* qbf = (unsigned short*)(ws + 0 * MB);   // 8MB; reused as Y later
  unsigned short* kbf = (unsigned short*)(ws + 8 * MB);   // 8MB
  unsigned short* vbf = (unsigned short*)(ws + 16 * MB);  // 8MB
  unsigned short* Wqt = (unsigned short*)(ws + 24 * MB);  // 2MB
  unsigned short* Wkt = (unsigned short*)(ws + 26 * MB);  // 2MB
  unsigned short* Wvt = (unsigned short*)(ws + 28 * MB);  // 2MB
  unsigned short* Wot = (unsigned short*)(ws + 30 * MB);  // 2MB
  unsigned short* Qh  = (unsigned short*)(ws + 32 * MB);  // 8MB [b][h][t][d]
  unsigned short* Kh  = (unsigned short*)(ws + 40 * MB);  // 8MB [b][h][t][d]
  unsigned short* Vth = (unsigned short*)(ws + 48 * MB);  // 8MB [b][h][d][t]
  unsigned short* Y   = qbf;  // alias: qbf is dead after gemm_qkv_k

  cvt3_k<<<dim3(2048, 3), 256, 0, stream>>>(q, k, v, qbf, kbf, vbf);
  wtrans4_k<<<dim3(32, 32, 4), dim3(32, 8), 0, stream>>>(Wq, Wk, Wv, Wo, Wqt, Wkt, Wvt, Wot);
  gemm_qkv_k<<<dim3(768), 256, 0, stream>>>(qbf, kbf, vbf, Wqt, Wkt, Wvt,
                                            bq, bk, bv, Qh, Kh, Vth);
  attn_k<<<dim3(4096), 1024, 78656, stream>>>(Qh, Kh, Vth, Y);
  gemm_out_k<<<dim3(256), 256, 0, stream>>>(Y, Wot, bo, (float*)d_out);
}